// Round 19
// baseline (359.083 us; speedup 1.0000x reference)
//
#include <hip/hip_runtime.h>
#include <type_traits>

typedef unsigned short ushort_t;
typedef unsigned int   uint_t;
typedef __attribute__((ext_vector_type(8))) short bf16x8;
typedef __attribute__((ext_vector_type(4))) float f32x4;

constexpr int Bn = 4, Tn = 1024, Cn = 2048, NH = 16, HS = 128;
constexpr int NLQ = 1536, NLKV = 512, DHR = 64;
constexpr int BT = Bn * Tn;
constexpr int KLD = 640;                  // kfull leading dim (512 ckv + 64 kr + 64 pad)
constexpr float ATT_SCALE = 0.07216878364870323f; // 1/sqrt(192)
constexpr float LOG2E = 1.4426950408889634f;

__device__ __forceinline__ ushort_t f2bf(float f) {
    uint_t u = __float_as_uint(f);
    u += 0x7fffu + ((u >> 16) & 1u);   // RNE
    return (ushort_t)(u >> 16);
}

__device__ __forceinline__ void gload_lds16(const void* g, void* l) {
    __builtin_amdgcn_global_load_lds(
        (__attribute__((address_space(1))) void*)g,
        (__attribute__((address_space(3))) void*)l, 16, 0, 0);
}

__device__ __forceinline__ void pipe_wait4(bool last) {
    if (last) asm volatile("s_waitcnt vmcnt(0)" ::: "memory");
    else      asm volatile("s_waitcnt vmcnt(4)" ::: "memory");
    __builtin_amdgcn_s_barrier();
    asm volatile("" ::: "memory");
}

// LDS swizzle (rule #21): linear gload_lds dest + inverse-swizzled GLOBAL src
// + swizzled read. Slot key = ((row & 15) >> 1) & 3; row bases are 16-aligned.

// ---------------------------------------------------------------------------
// 128x128 tile accumulator core: triple-buffered counted-vmcnt pipeline +
// swizzle. Leaves results in acc; callers write their own epilogue.
// ---------------------------------------------------------------------------
__device__ __forceinline__ void gemm_acc_pipe(
    const ushort_t* __restrict__ Ab, int lda,
    const ushort_t* __restrict__ Bb, int ldb, int K,
    ushort_t* As, ushort_t* Bs, f32x4 (&acc)[4][4])
{
    const int tid  = threadIdx.x;
    const int lane = tid & 63;
    const int w    = tid >> 6;
    const int l15 = lane & 15, l4 = lane >> 4;
    const int wr = w >> 1, wc = w & 1;
    const int srow = lane >> 2;
    const int scolsw = (((lane & 3) ^ ((srow >> 1) & 3)) * 8);
    const int l4s8 = (l4 ^ ((l15 >> 1) & 3)) * 8;
    const int nT = K >> 5;

    auto stage = [&](int t) {
        const int buf = t % 3;
        const int k0 = t * 32;
        #pragma unroll
        for (int i = 0; i < 2; ++i) {
            int r = w * 32 + i * 16;
            gload_lds16(Ab + (long)(r + srow) * lda + k0 + scolsw, &As[buf * 4096 + r * 32]);
            gload_lds16(Bb + (long)(r + srow) * ldb + k0 + scolsw, &Bs[buf * 4096 + r * 32]);
        }
    };

    #pragma unroll
    for (int m = 0; m < 4; ++m)
        #pragma unroll
        for (int n = 0; n < 4; ++n) acc[m][n] = (f32x4){0.f, 0.f, 0.f, 0.f};

    stage(0);
    if (nT > 1) stage(1);

    for (int t = 0; t < nT; ++t) {
        pipe_wait4(t + 1 >= nT);
        if (t + 2 < nT) stage(t + 2);
        const int buf = t % 3;
        bf16x8 af[4], bfv[4];
        #pragma unroll
        for (int m = 0; m < 4; ++m)
            af[m] = *(const bf16x8*)&As[buf * 4096 + (wr * 64 + m * 16 + l15) * 32 + l4s8];
        #pragma unroll
        for (int n = 0; n < 4; ++n)
            bfv[n] = *(const bf16x8*)&Bs[buf * 4096 + (wc * 64 + n * 16 + l15) * 32 + l4s8];
        #pragma unroll
        for (int m = 0; m < 4; ++m)
            #pragma unroll
            for (int n = 0; n < 4; ++n)
                acc[m][n] = __builtin_amdgcn_mfma_f32_16x16x32_bf16(af[m], bfv[n], acc[m][n], 0, 0, 0);
    }
}

// plain bf16 epilogue
__device__ __forceinline__ void epi_bf16(f32x4 (&acc)[4][4], ushort_t* Cb, int ldc) {
    const int lane = threadIdx.x & 63;
    const int w    = threadIdx.x >> 6;
    const int l15 = lane & 15, l4 = lane >> 4;
    const int wr = w >> 1, wc = w & 1;
    #pragma unroll
    for (int m = 0; m < 4; ++m)
        #pragma unroll
        for (int j = 0; j < 4; ++j) {
            long row = wr * 64 + m * 16 + l4 * 4 + j;
            #pragma unroll
            for (int n = 0; n < 4; ++n)
                Cb[row * ldc + wc * 64 + n * 16 + l15] = f2bf(acc[m][n][j]);
        }
}

// ---------------------------------------------------------------------------
// g1_mt: group1 [c_q | c_kv|c_kr] (544 blocks, rope_kr fused into the kr
// columns) + Mt GEMM (64 tail blocks).
// ---------------------------------------------------------------------------
__global__ __launch_bounds__(256, 2) void g1_mt(
    const ushort_t* __restrict__ xb, const ushort_t* __restrict__ WB1,
    ushort_t* __restrict__ cq_b, ushort_t* __restrict__ kfull,
    const ushort_t* __restrict__ Wo_b, const ushort_t* __restrict__ WuvT_b,
    ushort_t* __restrict__ Mtb,
    const float* __restrict__ cosT, const float* __restrict__ sinT)
{
    __shared__ ushort_t As[3 * 4096];
    __shared__ ushort_t Bs[3 * 4096];
    f32x4 acc[4][4];
    const int id = blockIdx.x;
    const int lane = threadIdx.x & 63;
    const int w    = threadIdx.x >> 6;
    const int l15 = lane & 15, l4 = lane >> 4;
    const int wr = w >> 1, wc = w & 1;

    if (id < 544) {
        const int sid = (id & 7) * 68 + (id >> 3);
        const int nt = sid % 17, mt = sid / 17;
        gemm_acc_pipe(xb + (long)mt * 128 * Cn, Cn, WB1 + (long)nt * 128 * Cn, Cn, Cn,
                      As, Bs, acc);
        if (nt < 12) {
            epi_bf16(acc, cq_b + (long)mt * 128 * NLQ + nt * 128, NLQ);
        } else if (nt < 16 || wc == 1) {       // c_kv cols or pad: plain store
            ushort_t* Cb = kfull + (long)mt * 128 * KLD + (nt - 12) * 128;
            epi_bf16(acc, Cb, KLD);
        } else {                                // nt==16, wc==0: kr cols, fused rope
            ushort_t* Cb = kfull + (long)mt * 128 * KLD + 512;
            #pragma unroll
            for (int m = 0; m < 4; ++m)
                #pragma unroll
                for (int j = 0; j < 4; ++j) {
                    long rowl = wr * 64 + m * 16 + l4 * 4 + j;      // LOCAL row
                    int t = (int)((mt * 128 + rowl) & 1023);        // global t for angle
                    #pragma unroll
                    for (int n = 0; n < 4; ++n) {
                        float v = acc[m][n][j];
                        float vr = __shfl_xor(v, 1);
                        int col = n * 16 + l15;            // 0..63
                        int i = col >> 1;
                        float c = cosT[t * 32 + i], s = sinT[t * 32 + i];
                        float o = ((l15 & 1) == 0) ? (v * c - vr * s) : (vr * s + v * c);
                        Cb[rowl * KLD + col] = f2bf(o);
                    }
                }
        }
    } else {
        const int local = id - 544;            // Mt = Wo @ WuvT^T (2048x512, K=2048)
        const int mt = local >> 2, nt = local & 3;
        gemm_acc_pipe(Wo_b + (long)mt * 128 * Cn, Cn, WuvT_b + (long)nt * 128 * Cn, Cn, Cn,
                      As, Bs, acc);
        epi_bf16(acc, Mtb + (long)mt * 128 * NLKV + nt * 128, NLKV);
    }
}

// ---------------------------------------------------------------------------
// g23: group2 [q_nom | c_qr(roped)] (768 blocks) + group3 [kabs | Veff]
// (1024 blocks). Independent workloads, one launch.
// ---------------------------------------------------------------------------
__global__ __launch_bounds__(256, 2) void g23(
    const ushort_t* __restrict__ cq_b, const ushort_t* __restrict__ WB2,
    ushort_t* __restrict__ qnom, ushort_t* __restrict__ qr_b,
    const ushort_t* __restrict__ kfull, const ushort_t* __restrict__ WB3,
    ushort_t* __restrict__ kabs, ushort_t* __restrict__ Veff,
    const float* __restrict__ cosT, const float* __restrict__ sinT)
{
    __shared__ ushort_t As[3 * 4096];
    __shared__ ushort_t Bs[3 * 4096];
    f32x4 acc[4][4];
    const int id = blockIdx.x;
    const int lane = threadIdx.x & 63;
    const int w    = threadIdx.x >> 6;
    const int l15 = lane & 15, l4 = lane >> 4;
    const int wr = w >> 1, wc = w & 1;

    if (id < 768) {                            // group2, K=1536
        const int sid = (id & 7) * 96 + (id >> 3);
        const int nt = sid % 24, mt = sid / 24;
        gemm_acc_pipe(cq_b + (long)mt * 128 * NLQ, NLQ, WB2 + (long)nt * 128 * NLQ, NLQ, NLQ,
                      As, Bs, acc);
        if (nt < 16) {
            epi_bf16(acc, qnom + (long)mt * 128 * Cn + nt * 128, Cn);
        } else {                                // c_qr with fused rope
            ushort_t* Cb = qr_b + (long)mt * 128 * (NH * DHR) + (nt - 16) * 128;
            #pragma unroll
            for (int m = 0; m < 4; ++m)
                #pragma unroll
                for (int j = 0; j < 4; ++j) {
                    long rowl = wr * 64 + m * 16 + l4 * 4 + j;      // LOCAL row
                    int t = (int)((mt * 128 + rowl) & 1023);
                    #pragma unroll
                    for (int n = 0; n < 4; ++n) {
                        float v = acc[m][n][j];
                        float vr = __shfl_xor(v, 1);
                        int colg = (nt - 16) * 128 + wc * 64 + n * 16 + l15; // 0..1023
                        int i = (colg & 63) >> 1;
                        float c = cosT[t * 32 + i], s = sinT[t * 32 + i];
                        float o = ((l15 & 1) == 0) ? (v * c - vr * s) : (vr * s + v * c);
                        Cb[rowl * (NH * DHR) + wc * 64 + n * 16 + l15] = f2bf(o);
                    }
                }
        }
    } else {                                   // group3, K=512
        const int local = id - 768;
        const int sid = (local & 7) * 128 + (local >> 3);
        const int nt = sid % 32, mt = sid / 32;
        gemm_acc_pipe(kfull + (long)mt * 128 * KLD, KLD, WB3 + (long)nt * 128 * NLKV, NLKV, NLKV,
                      As, Bs, acc);
        if (nt < 16) epi_bf16(acc, kabs + (long)mt * 128 * Cn + nt * 128, Cn);
        else         epi_bf16(acc, Veff + (long)mt * 128 * Cn + (nt - 16) * 128, Cn);
    }
}

// ---------------------------------------------------------------------------
// attn_s (2304 blocks, K=192 packed S) + transpose_veff tail (4096 blocks).
// ---------------------------------------------------------------------------
__global__ __launch_bounds__(256, 2) void attn_s_tv(
    const ushort_t* __restrict__ qnom, const ushort_t* __restrict__ qrb,
    const ushort_t* __restrict__ kabs, const ushort_t* __restrict__ kfull,
    ushort_t* __restrict__ Spk,
    const ushort_t* __restrict__ Veff, ushort_t* __restrict__ VeffT)
{
    __shared__ ushort_t As[3 * 4096];
    __shared__ ushort_t Bs[3 * 4096];
    const int id = blockIdx.x;
    if (id >= 2304) {                          // transpose_veff
        int idx = (id - 2304) * 256 + threadIdx.x;
        int c = idx & 2047, rest = idx >> 11;
        int t8 = rest & 127, b = rest >> 7;
        ushort_t v[8];
        #pragma unroll
        for (int j = 0; j < 8; ++j)
            v[j] = Veff[((long)b * Tn + t8 * 8 + j) * 2048 + c];
        *(uint4*)&VeffT[((long)b * 2048 + c) * Tn + t8 * 8] = *(const uint4*)v;
        return;
    }
    const int sid = (id & 7) * 288 + (id >> 3);
    const int x = sid % 36, z = sid / 36;
    int ti = 0;
    while ((ti + 1) * (ti + 2) / 2 <= x) ++ti;
    const int si = x - ti * (ti + 1) / 2;
    const int h = z >> 2, b = z & 3;

    const int tid  = threadIdx.x;
    const int lane = tid & 63;
    const int w    = tid >> 6;
    const int l15 = lane & 15, l4 = lane >> 4;
    const int wr = w >> 1, wc = w & 1;
    const int srow = lane >> 2;
    const int scolsw = (((lane & 3) ^ ((srow >> 1) & 3)) * 8);
    const int l4s8 = (l4 ^ ((l15 >> 1) & 3)) * 8;

    const ushort_t* A1 = qnom + ((long)(b * 1024 + ti * 128)) * 2048 + h * 128;
    const ushort_t* A2 = qrb  + ((long)(b * 1024 + ti * 128)) * 1024 + h * 64;
    const ushort_t* B1 = kabs + ((long)(b * 1024 + si * 128)) * 2048 + h * 128;
    const ushort_t* B2 = kfull + ((long)(b * 1024 + si * 128)) * KLD + 512;
    ushort_t* Cb = Spk + (long)z * 589824 + (long)x * 16384;

    auto stage = [&](int t) {
        const int buf = t % 3;
        const ushort_t* Asrc; const ushort_t* Bsrc; int ldA, ldB;
        if (t < 4) { Asrc = A1 + t * 32;       Bsrc = B1 + t * 32;       ldA = 2048; ldB = 2048; }
        else       { Asrc = A2 + (t - 4) * 32; Bsrc = B2 + (t - 4) * 32; ldA = 1024; ldB = KLD; }
        #pragma unroll
        for (int i = 0; i < 2; ++i) {
            int r = w * 32 + i * 16;
            gload_lds16(Asrc + (long)(r + srow) * ldA + scolsw, &As[buf * 4096 + r * 32]);
            gload_lds16(Bsrc + (long)(r + srow) * ldB + scolsw, &Bs[buf * 4096 + r * 32]);
        }
    };

    f32x4 acc[4][4];
    #pragma unroll
    for (int m = 0; m < 4; ++m)
        #pragma unroll
        for (int n = 0; n < 4; ++n) acc[m][n] = (f32x4){0.f, 0.f, 0.f, 0.f};

    stage(0); stage(1);
    #pragma unroll
    for (int t = 0; t < 6; ++t) {
        pipe_wait4(t == 5);
        if (t + 2 < 6) stage(t + 2);
        const int buf = t % 3;
        bf16x8 af[4], bfv[4];
        #pragma unroll
        for (int m = 0; m < 4; ++m)
            af[m] = *(const bf16x8*)&As[buf * 4096 + (wr * 64 + m * 16 + l15) * 32 + l4s8];
        #pragma unroll
        for (int n = 0; n < 4; ++n)
            bfv[n] = *(const bf16x8*)&Bs[buf * 4096 + (wc * 64 + n * 16 + l15) * 32 + l4s8];
        #pragma unroll
        for (int m = 0; m < 4; ++m)
            #pragma unroll
            for (int n = 0; n < 4; ++n)
                acc[m][n] = __builtin_amdgcn_mfma_f32_16x16x32_bf16(af[m], bfv[n], acc[m][n], 0, 0, 0);
    }

    #pragma unroll
    for (int m = 0; m < 4; ++m)
        #pragma unroll
        for (int j = 0; j < 4; ++j) {
            long row = wr * 64 + m * 16 + l4 * 4 + j;
            #pragma unroll
            for (int n = 0; n < 4; ++n)
                Cb[row * 128 + wc * 64 + n * 16 + l15] = f2bf(acc[m][n][j]);
        }
}

// ---------------------------------------------------------------------------
// attn_pv_sm: fused causal softmax (block-local rows) + PV GEMM -> out (f32).
// Each block (ti,z) softmaxes exactly the 128 P-rows it consumes.
// ---------------------------------------------------------------------------
__global__ __launch_bounds__(256, 2) void attn_pv_sm(
    ushort_t* __restrict__ Spk, const ushort_t* __restrict__ VeffT,
    float* __restrict__ out)
{
    __shared__ ushort_t As[3 * 4096];
    __shared__ ushort_t Bs[3 * 4096];
    const int id  = blockIdx.x;
    const int sid = (id & 7) * 64 + (id >> 3);
    const int ti = sid & 7, z = sid >> 3;
    const int tid  = threadIdx.x;
    const int lane = tid & 63;
    const int w    = tid >> 6;
    const int l15 = lane & 15, l4 = lane >> 4;
    const int wr = w >> 1, wc = w & 1;
    const int srow = lane >> 2;
    const int scolsw = (((lane & 3) ^ ((srow >> 1) & 3)) * 8);
    const int l4s8 = (l4 ^ ((l15 >> 1) & 3)) * 8;
    const int h = z >> 2, b = z & 3;
    const int nT = (ti + 1) * 4;
    ushort_t* Az = Spk + (long)z * 589824 + (long)(ti * (ti + 1) / 2) * 16384;

    // ---- softmax prologue: wave w handles rows w*32 .. w*32+31
    {
        const int nc = ti + 1;
        const float SCL = ATT_SCALE * LOG2E;
        for (int r_i = 0; r_i < 32; ++r_i) {
            const int rloc = w * 32 + r_i;
            const int t = ti * 128 + rloc;
            ushort_t* rowb = Az + rloc * 128 + lane * 2;
            float p0[8], p1[8];
            float mx = -INFINITY;
            #pragma unroll
            for (int c = 0; c < 8; ++c) {
                p0[c] = -INFINITY; p1[c] = -INFINITY;
                if (c < nc) {
                    uint_t u = *(const uint_t*)&rowb[c * 16384];
                    int kv = c * 128 + lane * 2;
                    float a  = __uint_as_float(u << 16);
                    float bb = __uint_as_float(u & 0xffff0000u);
                    if (kv     <= t) p0[c] = a  * SCL;
                    if (kv + 1 <= t) p1[c] = bb * SCL;
                    mx = fmaxf(mx, fmaxf(p0[c], p1[c]));
                }
            }
            #pragma unroll
            for (int off = 32; off >= 1; off >>= 1) mx = fmaxf(mx, __shfl_xor(mx, off));
            float s = 0.f;
            #pragma unroll
            for (int c = 0; c < 8; ++c) {
                p0[c] = exp2f(p0[c] - mx);
                p1[c] = exp2f(p1[c] - mx);
                if (c < nc) s += p0[c] + p1[c];
            }
            #pragma unroll
            for (int off = 32; off >= 1; off >>= 1) s += __shfl_xor(s, off);
            const float inv = 1.f / s;
            #pragma unroll
            for (int c = 0; c < 8; ++c) if (c < nc) {
                uint_t o = (uint_t)f2bf(p0[c] * inv) | ((uint_t)f2bf(p1[c] * inv) << 16);
                *(uint_t*)&rowb[c * 16384] = o;
            }
        }
    }
    asm volatile("s_waitcnt vmcnt(0)" ::: "memory");
    __syncthreads();

    // ---- PV GEMM
    const ushort_t* Bb = VeffT + ((long)b * 2048 + h * 128) * 1024;
    float* Cb = out + ((long)b * 1024 + ti * 128) * 2048 + h * 128;

    auto stage = [&](int t) {
        const int buf = t % 3;
        const int k0 = t * 32;
        const ushort_t* At = Az + (k0 >> 7) * 16384 + (k0 & 127);
        #pragma unroll
        for (int i = 0; i < 2; ++i) {
            int r = w * 32 + i * 16;
            gload_lds16(At + (long)(r + srow) * 128 + scolsw, &As[buf * 4096 + r * 32]);
            gload_lds16(Bb + (long)(r + srow) * 1024 + k0 + scolsw, &Bs[buf * 4096 + r * 32]);
        }
    };

    f32x4 acc[4][4];
    #pragma unroll
    for (int m = 0; m < 4; ++m)
        #pragma unroll
        for (int n = 0; n < 4; ++n) acc[m][n] = (f32x4){0.f, 0.f, 0.f, 0.f};

    stage(0); stage(1);
    for (int t = 0; t < nT; ++t) {
        pipe_wait4(t + 1 >= nT);
        if (t + 2 < nT) stage(t + 2);
        const int buf = t % 3;
        bf16x8 af[4], bfv[4];
        #pragma unroll
        for (int m = 0; m < 4; ++m)
            af[m] = *(const bf16x8*)&As[buf * 4096 + (wr * 64 + m * 16 + l15) * 32 + l4s8];
        #pragma unroll
        for (int n = 0; n < 4; ++n)
            bfv[n] = *(const bf16x8*)&Bs[buf * 4096 + (wc * 64 + n * 16 + l15) * 32 + l4s8];
        #pragma unroll
        for (int m = 0; m < 4; ++m)
            #pragma unroll
            for (int n = 0; n < 4; ++n)
                acc[m][n] = __builtin_amdgcn_mfma_f32_16x16x32_bf16(af[m], bfv[n], acc[m][n], 0, 0, 0);
    }

    #pragma unroll
    for (int m = 0; m < 4; ++m)
        #pragma unroll
        for (int j = 0; j < 4; ++j) {
            long row = wr * 64 + m * 16 + l4 * 4 + j;
            #pragma unroll
            for (int n = 0; n < 4; ++n)
                Cb[row * 2048 + wc * 64 + n * 16 + l15] = acc[m][n][j];
        }
}

// ---------------------------------------------------------------------------
// prep_all: fused conversions + transposes (range dispatch).
// ---------------------------------------------------------------------------
__global__ __launch_bounds__(256) void prep_all(
    const float* __restrict__ x,    const float* __restrict__ Wdq,
    const float* __restrict__ Wdkv, const float* __restrict__ Wkr,
    const float* __restrict__ Wqr,  const float* __restrict__ Wo,
    const float* __restrict__ Wuk,  const float* __restrict__ Wuq,
    const float* __restrict__ Wuv,
    ushort_t* __restrict__ xb, ushort_t* __restrict__ WB1,
    ushort_t* __restrict__ WB2, ushort_t* __restrict__ Wo_b,
    ushort_t* __restrict__ WB3, ushort_t* __restrict__ WuvT_b)
{
    const int bid = blockIdx.x;
    const int t = threadIdx.x;

    if (bid >= 9600) {
        __shared__ float tile[64][65];
        const float* in; ushort_t* outp; int ldin, R, c0, r0;
        if (bid < 10368) { int l = bid - 9600;  in = Wuq; outp = WB2;    ldin = 2048; R = 1536; c0 = (l % 32) * 64; r0 = (l / 32) * 64; }
        else             { int l = bid - 10368; in = Wuv; outp = WuvT_b; ldin = 512;  R = 2048; c0 = (l % 8) * 64;  r0 = (l / 8) * 64; }
        #pragma unroll
        for (int i = 0; i < 4; ++i) {
            int idx = t + i * 256;
            int r = idx >> 4, c4 = idx & 15;
            float4 v = *(const float4*)&in[(long)(r0 + r) * ldin + c0 + c4 * 4];
            tile[r][c4 * 4 + 0] = v.x; tile[r][c4 * 4 + 1] = v.y;
            tile[r][c4 * 4 + 2] = v.z; tile[r][c4 * 4 + 3] = v.w;
        }
        __syncthreads();
        #pragma unroll
        for (int i = 0; i < 4; ++i) {
            int idx = t + i * 256;
            int c = idx >> 4, r4 = idx & 15;
            ushort_t p[4];
            #pragma unroll
            for (int j = 0; j < 4; ++j) p[j] = f2bf(tile[r4 * 4 + j][c]);
            *(uint2*)&outp[(long)(c0 + c) * R + r0 + r4 * 4] = *(const uint2*)p;
        }
        return;
    }

    const float* src = nullptr; ushort_t* dst;
    if      (bid < 4096) { src = x    + (long)bid * 2048;          dst = xb   + (long)bid * 2048; }
    else if (bid < 5632) { long b = bid - 4096; src = Wdq  + b * 2048; dst = WB1 + b * 2048; }
    else if (bid < 6144) { long b = bid - 5632; src = Wdkv + b * 2048; dst = WB1 + 3145728 + b * 2048; }
    else if (bid < 6208) { long b = bid - 6144; src = Wkr  + b * 2048; dst = WB1 + 4194304 + b * 2048; }
    else if (bid < 6272) { long b = bid - 6208;                        dst = WB1 + 4325376 + b * 2048; }
    else if (bid < 7040) { long b = bid - 6272; src = Wqr  + b * 2048; dst = WB2 + 3145728 + b * 2048; }
    else if (bid < 9088) { long b = bid - 7040; src = Wo   + b * 2048; dst = Wo_b + b * 2048; }
    else                 { long b = bid - 9088; src = Wuk  + b * 2048; dst = WB3 + b * 2048; }

    const long i = (long)t * 8;
    if (!src) { *(uint4*)&dst[i] = make_uint4(0, 0, 0, 0); return; }
    float4 a = *(const float4*)&src[i];
    float4 b4 = *(const float4*)&src[i + 4];
    ushort_t p[8] = {f2bf(a.x), f2bf(a.y), f2bf(a.z), f2bf(a.w),
                     f2bf(b4.x), f2bf(b4.y), f2bf(b4.z), f2bf(b4.w)};
    *(uint4*)&dst[i] = *(const uint4*)p;
}

// ---------------------------------------------------------------------------
extern "C" void kernel_launch(void* const* d_in, const int* in_sizes, int n_in,
                              void* d_out, int out_size, void* d_ws, size_t ws_size,
                              hipStream_t stream)
{
    (void)in_sizes; (void)n_in; (void)out_size; (void)ws_size;
    const float* x     = (const float*)d_in[0];
    const float* cosT  = (const float*)d_in[1];
    const float* sinT  = (const float*)d_in[2];
    const float* W_dq  = (const float*)d_in[3];
    const float* W_uq  = (const float*)d_in[4];
    const float* W_dkv = (const float*)d_in[5];
    const float* W_uk  = (const float*)d_in[6];
    const float* W_uv  = (const float*)d_in[7];
    const float* W_qr  = (const float*)d_in[8];
    const float* W_kr  = (const float*)d_in[9];
    const float* W_o   = (const float*)d_in[10];
    float* out = (float*)d_out;

    // ---- workspace: 79,953,920 ushorts = 159.9 MB ----
    ushort_t* ws = (ushort_t*)d_ws;
    ushort_t* xb     = ws;                              // 8388608
    ushort_t* WB1    = ws + 8388608;                    // 4456448  [2176][2048]
    ushort_t* WB2    = ws + 12845056;                   // 4718592  [3072][1536] = WuqT|Wqr
    ushort_t* Wo_b   = ws + 17563648;                   // 4194304  [2048][2048]
    ushort_t* WuvT_b = ws + 21757952;                   // 1048576  [512][2048]
    ushort_t* cq_b   = ws + 22806528;                   // 6291456  [4096][1536]
    ushort_t* WB3    = ws + 29097984;                   // 2097152  [4096][512] = Wuk|Mt
    ushort_t* Spk    = ws;                              // 37748736 [64 z][36][128][128]
    // PERSISTENT:
    ushort_t* qnom   = ws + 39583744;                   // 8388608
    ushort_t* qr_b   = ws + 47972352;                   // 4194304
    ushort_t* kabs   = ws + 52166656;                   // 8388608
    ushort_t* kfull  = ws + 60555264;                   // 2621440  [4096][640]
    ushort_t* VeffT  = ws + 63176704;                   // 8388608  [4][2048][1024]
    ushort_t* Veff   = ws + 71565312;                   // 8388608  (lives past attn_s)
    ushort_t* Mtb    = WB3 + 1048576;

    dim3 blk(256, 1, 1);

    // 1) conversions + transposes (fused)
    prep_all<<<dim3(10624), blk, 0, stream>>>(
        x, W_dq, W_dkv, W_kr, W_qr, W_o, W_uk, W_uq, W_uv,
        xb, WB1, WB2, Wo_b, WB3, WuvT_b);

    // 2) group1 (fused rope_kr) + Mt
    g1_mt<<<dim3(608), blk, 0, stream>>>(xb, WB1, cq_b, kfull, Wo_b, WuvT_b, Mtb,
                                         cosT, sinT);

    // 3) group2 (fused rope_qr) + group3
    g23<<<dim3(1792), blk, 0, stream>>>(cq_b, WB2, qnom, qr_b, kfull, WB3,
                                        kabs, Veff, cosT, sinT);

    // 4) attn_s + transpose_veff
    attn_s_tv<<<dim3(6400), blk, 0, stream>>>(qnom, qr_b, kabs, kfull, Spk, Veff, VeffT);

    // 5) fused softmax + PV -> out
    attn_pv_sm<<<dim3(512), blk, 0, stream>>>(Spk, VeffT, out);
}

// Round 20
// 279.292 us; speedup vs baseline: 1.2857x; 1.2857x over previous
//
#include <hip/hip_runtime.h>
#include <type_traits>

typedef unsigned short ushort_t;
typedef unsigned int   uint_t;
typedef __attribute__((ext_vector_type(8))) short bf16x8;
typedef __attribute__((ext_vector_type(4))) float f32x4;

constexpr int Bn = 4, Tn = 1024, Cn = 2048, NH = 16, HS = 128;
constexpr int NLQ = 1536, NLKV = 512, DHR = 64;
constexpr int BT = Bn * Tn;
constexpr int KLD = 640;                  // kfull leading dim (512 ckv + 64 kr + 64 pad)
constexpr float ATT_SCALE = 0.07216878364870323f; // 1/sqrt(192)
constexpr float LOG2E = 1.4426950408889634f;

__device__ __forceinline__ ushort_t f2bf(float f) {
    uint_t u = __float_as_uint(f);
    u += 0x7fffu + ((u >> 16) & 1u);   // RNE
    return (ushort_t)(u >> 16);
}

__device__ __forceinline__ void gload_lds16(const void* g, void* l) {
    __builtin_amdgcn_global_load_lds(
        (__attribute__((address_space(1))) void*)g,
        (__attribute__((address_space(3))) void*)l, 16, 0, 0);
}

__device__ __forceinline__ void pipe_wait4(bool last) {
    if (last) asm volatile("s_waitcnt vmcnt(0)" ::: "memory");
    else      asm volatile("s_waitcnt vmcnt(4)" ::: "memory");
    __builtin_amdgcn_s_barrier();
    asm volatile("" ::: "memory");
}

// LDS swizzle (rule #21): linear gload_lds dest + inverse-swizzled GLOBAL src
// + swizzled read. Slot key = ((row & 15) >> 1) & 3; row bases are 16-aligned.

// ---------------------------------------------------------------------------
// 128x128 tile accumulator core: triple-buffered counted-vmcnt pipeline +
// swizzle. Leaves results in acc; callers write their own epilogue.
// ---------------------------------------------------------------------------
__device__ __forceinline__ void gemm_acc_pipe(
    const ushort_t* __restrict__ Ab, int lda,
    const ushort_t* __restrict__ Bb, int ldb, int K,
    ushort_t* As, ushort_t* Bs, f32x4 (&acc)[4][4])
{
    const int tid  = threadIdx.x;
    const int lane = tid & 63;
    const int w    = tid >> 6;
    const int l15 = lane & 15, l4 = lane >> 4;
    const int wr = w >> 1, wc = w & 1;
    const int srow = lane >> 2;
    const int scolsw = (((lane & 3) ^ ((srow >> 1) & 3)) * 8);
    const int l4s8 = (l4 ^ ((l15 >> 1) & 3)) * 8;
    const int nT = K >> 5;

    auto stage = [&](int t) {
        const int buf = t % 3;
        const int k0 = t * 32;
        #pragma unroll
        for (int i = 0; i < 2; ++i) {
            int r = w * 32 + i * 16;
            gload_lds16(Ab + (long)(r + srow) * lda + k0 + scolsw, &As[buf * 4096 + r * 32]);
            gload_lds16(Bb + (long)(r + srow) * ldb + k0 + scolsw, &Bs[buf * 4096 + r * 32]);
        }
    };

    #pragma unroll
    for (int m = 0; m < 4; ++m)
        #pragma unroll
        for (int n = 0; n < 4; ++n) acc[m][n] = (f32x4){0.f, 0.f, 0.f, 0.f};

    stage(0);
    if (nT > 1) stage(1);

    for (int t = 0; t < nT; ++t) {
        pipe_wait4(t + 1 >= nT);
        if (t + 2 < nT) stage(t + 2);
        const int buf = t % 3;
        bf16x8 af[4], bfv[4];
        #pragma unroll
        for (int m = 0; m < 4; ++m)
            af[m] = *(const bf16x8*)&As[buf * 4096 + (wr * 64 + m * 16 + l15) * 32 + l4s8];
        #pragma unroll
        for (int n = 0; n < 4; ++n)
            bfv[n] = *(const bf16x8*)&Bs[buf * 4096 + (wc * 64 + n * 16 + l15) * 32 + l4s8];
        #pragma unroll
        for (int m = 0; m < 4; ++m)
            #pragma unroll
            for (int n = 0; n < 4; ++n)
                acc[m][n] = __builtin_amdgcn_mfma_f32_16x16x32_bf16(af[m], bfv[n], acc[m][n], 0, 0, 0);
    }
}

// plain bf16 epilogue
__device__ __forceinline__ void epi_bf16(f32x4 (&acc)[4][4], ushort_t* Cb, int ldc) {
    const int lane = threadIdx.x & 63;
    const int w    = threadIdx.x >> 6;
    const int l15 = lane & 15, l4 = lane >> 4;
    const int wr = w >> 1, wc = w & 1;
    #pragma unroll
    for (int m = 0; m < 4; ++m)
        #pragma unroll
        for (int j = 0; j < 4; ++j) {
            long row = wr * 64 + m * 16 + l4 * 4 + j;
            #pragma unroll
            for (int n = 0; n < 4; ++n)
                Cb[row * ldc + wc * 64 + n * 16 + l15] = f2bf(acc[m][n][j]);
        }
}

// ---------------------------------------------------------------------------
// g1_mt: group1 [c_q | c_kv|c_kr] (544 blocks, rope_kr fused into the kr
// columns) + Mt GEMM (64 tail blocks).
// ---------------------------------------------------------------------------
__global__ __launch_bounds__(256, 2) void g1_mt(
    const ushort_t* __restrict__ xb, const ushort_t* __restrict__ WB1,
    ushort_t* __restrict__ cq_b, ushort_t* __restrict__ kfull,
    const ushort_t* __restrict__ Wo_b, const ushort_t* __restrict__ WuvT_b,
    ushort_t* __restrict__ Mtb,
    const float* __restrict__ cosT, const float* __restrict__ sinT)
{
    __shared__ ushort_t As[3 * 4096];
    __shared__ ushort_t Bs[3 * 4096];
    f32x4 acc[4][4];
    const int id = blockIdx.x;
    const int lane = threadIdx.x & 63;
    const int w    = threadIdx.x >> 6;
    const int l15 = lane & 15, l4 = lane >> 4;
    const int wr = w >> 1, wc = w & 1;

    if (id < 544) {
        const int sid = (id & 7) * 68 + (id >> 3);
        const int nt = sid % 17, mt = sid / 17;
        gemm_acc_pipe(xb + (long)mt * 128 * Cn, Cn, WB1 + (long)nt * 128 * Cn, Cn, Cn,
                      As, Bs, acc);
        if (nt < 12) {
            epi_bf16(acc, cq_b + (long)mt * 128 * NLQ + nt * 128, NLQ);
        } else if (nt < 16 || wc == 1) {       // c_kv cols or pad: plain store
            ushort_t* Cb = kfull + (long)mt * 128 * KLD + (nt - 12) * 128;
            epi_bf16(acc, Cb, KLD);
        } else {                                // nt==16, wc==0: kr cols, fused rope
            ushort_t* Cb = kfull + (long)mt * 128 * KLD + 512;
            #pragma unroll
            for (int m = 0; m < 4; ++m)
                #pragma unroll
                for (int j = 0; j < 4; ++j) {
                    long rowl = wr * 64 + m * 16 + l4 * 4 + j;      // LOCAL row
                    int t = (int)((mt * 128 + rowl) & 1023);        // global t for angle
                    #pragma unroll
                    for (int n = 0; n < 4; ++n) {
                        float v = acc[m][n][j];
                        float vr = __shfl_xor(v, 1);
                        int col = n * 16 + l15;            // 0..63
                        int i = col >> 1;
                        float c = cosT[t * 32 + i], s = sinT[t * 32 + i];
                        float o = ((l15 & 1) == 0) ? (v * c - vr * s) : (vr * s + v * c);
                        Cb[rowl * KLD + col] = f2bf(o);
                    }
                }
        }
    } else {
        const int local = id - 544;            // Mt = Wo @ WuvT^T (2048x512, K=2048)
        const int mt = local >> 2, nt = local & 3;
        gemm_acc_pipe(Wo_b + (long)mt * 128 * Cn, Cn, WuvT_b + (long)nt * 128 * Cn, Cn, Cn,
                      As, Bs, acc);
        epi_bf16(acc, Mtb + (long)mt * 128 * NLKV + nt * 128, NLKV);
    }
}

// ---------------------------------------------------------------------------
// g23: group2 [q_nom | c_qr(roped)] (768 blocks) + group3 [kabs | Veff]
// (1024 blocks). Independent workloads, one launch.
// ---------------------------------------------------------------------------
__global__ __launch_bounds__(256, 2) void g23(
    const ushort_t* __restrict__ cq_b, const ushort_t* __restrict__ WB2,
    ushort_t* __restrict__ qnom, ushort_t* __restrict__ qr_b,
    const ushort_t* __restrict__ kfull, const ushort_t* __restrict__ WB3,
    ushort_t* __restrict__ kabs, ushort_t* __restrict__ Veff,
    const float* __restrict__ cosT, const float* __restrict__ sinT)
{
    __shared__ ushort_t As[3 * 4096];
    __shared__ ushort_t Bs[3 * 4096];
    f32x4 acc[4][4];
    const int id = blockIdx.x;
    const int lane = threadIdx.x & 63;
    const int w    = threadIdx.x >> 6;
    const int l15 = lane & 15, l4 = lane >> 4;
    const int wr = w >> 1, wc = w & 1;

    if (id < 768) {                            // group2, K=1536
        const int sid = (id & 7) * 96 + (id >> 3);
        const int nt = sid % 24, mt = sid / 24;
        gemm_acc_pipe(cq_b + (long)mt * 128 * NLQ, NLQ, WB2 + (long)nt * 128 * NLQ, NLQ, NLQ,
                      As, Bs, acc);
        if (nt < 16) {
            epi_bf16(acc, qnom + (long)mt * 128 * Cn + nt * 128, Cn);
        } else {                                // c_qr with fused rope
            ushort_t* Cb = qr_b + (long)mt * 128 * (NH * DHR) + (nt - 16) * 128;
            #pragma unroll
            for (int m = 0; m < 4; ++m)
                #pragma unroll
                for (int j = 0; j < 4; ++j) {
                    long rowl = wr * 64 + m * 16 + l4 * 4 + j;      // LOCAL row
                    int t = (int)((mt * 128 + rowl) & 1023);
                    #pragma unroll
                    for (int n = 0; n < 4; ++n) {
                        float v = acc[m][n][j];
                        float vr = __shfl_xor(v, 1);
                        int colg = (nt - 16) * 128 + wc * 64 + n * 16 + l15; // 0..1023
                        int i = (colg & 63) >> 1;
                        float c = cosT[t * 32 + i], s = sinT[t * 32 + i];
                        float o = ((l15 & 1) == 0) ? (v * c - vr * s) : (vr * s + v * c);
                        Cb[rowl * (NH * DHR) + wc * 64 + n * 16 + l15] = f2bf(o);
                    }
                }
        }
    } else {                                   // group3, K=512
        const int local = id - 768;
        const int sid = (local & 7) * 128 + (local >> 3);
        const int nt = sid % 32, mt = sid / 32;
        gemm_acc_pipe(kfull + (long)mt * 128 * KLD, KLD, WB3 + (long)nt * 128 * NLKV, NLKV, NLKV,
                      As, Bs, acc);
        if (nt < 16) epi_bf16(acc, kabs + (long)mt * 128 * Cn + nt * 128, Cn);
        else         epi_bf16(acc, Veff + (long)mt * 128 * Cn + (nt - 16) * 128, Cn);
    }
}

// ---------------------------------------------------------------------------
// attn_s: S lower-triangle tiles, packed Spk[z][x][128][128]. K=192. 2304 blocks.
// ---------------------------------------------------------------------------
__global__ __launch_bounds__(256, 2) void attn_s_gemm(
    const ushort_t* __restrict__ qnom, const ushort_t* __restrict__ qrb,
    const ushort_t* __restrict__ kabs, const ushort_t* __restrict__ kfull,
    ushort_t* __restrict__ Spk)
{
    __shared__ ushort_t As[3 * 4096];
    __shared__ ushort_t Bs[3 * 4096];
    const int id = blockIdx.x;
    const int sid = (id & 7) * 288 + (id >> 3);
    const int x = sid % 36, z = sid / 36;
    int ti = 0;
    while ((ti + 1) * (ti + 2) / 2 <= x) ++ti;
    const int si = x - ti * (ti + 1) / 2;
    const int h = z >> 2, b = z & 3;

    const int tid  = threadIdx.x;
    const int lane = tid & 63;
    const int w    = tid >> 6;
    const int l15 = lane & 15, l4 = lane >> 4;
    const int wr = w >> 1, wc = w & 1;
    const int srow = lane >> 2;
    const int scolsw = (((lane & 3) ^ ((srow >> 1) & 3)) * 8);
    const int l4s8 = (l4 ^ ((l15 >> 1) & 3)) * 8;

    const ushort_t* A1 = qnom + ((long)(b * 1024 + ti * 128)) * 2048 + h * 128;
    const ushort_t* A2 = qrb  + ((long)(b * 1024 + ti * 128)) * 1024 + h * 64;
    const ushort_t* B1 = kabs + ((long)(b * 1024 + si * 128)) * 2048 + h * 128;
    const ushort_t* B2 = kfull + ((long)(b * 1024 + si * 128)) * KLD + 512;
    ushort_t* Cb = Spk + (long)z * 589824 + (long)x * 16384;

    auto stage = [&](int t) {
        const int buf = t % 3;
        const ushort_t* Asrc; const ushort_t* Bsrc; int ldA, ldB;
        if (t < 4) { Asrc = A1 + t * 32;       Bsrc = B1 + t * 32;       ldA = 2048; ldB = 2048; }
        else       { Asrc = A2 + (t - 4) * 32; Bsrc = B2 + (t - 4) * 32; ldA = 1024; ldB = KLD; }
        #pragma unroll
        for (int i = 0; i < 2; ++i) {
            int r = w * 32 + i * 16;
            gload_lds16(Asrc + (long)(r + srow) * ldA + scolsw, &As[buf * 4096 + r * 32]);
            gload_lds16(Bsrc + (long)(r + srow) * ldB + scolsw, &Bs[buf * 4096 + r * 32]);
        }
    };

    f32x4 acc[4][4];
    #pragma unroll
    for (int m = 0; m < 4; ++m)
        #pragma unroll
        for (int n = 0; n < 4; ++n) acc[m][n] = (f32x4){0.f, 0.f, 0.f, 0.f};

    stage(0); stage(1);
    #pragma unroll
    for (int t = 0; t < 6; ++t) {
        pipe_wait4(t == 5);
        if (t + 2 < 6) stage(t + 2);
        const int buf = t % 3;
        bf16x8 af[4], bfv[4];
        #pragma unroll
        for (int m = 0; m < 4; ++m)
            af[m] = *(const bf16x8*)&As[buf * 4096 + (wr * 64 + m * 16 + l15) * 32 + l4s8];
        #pragma unroll
        for (int n = 0; n < 4; ++n)
            bfv[n] = *(const bf16x8*)&Bs[buf * 4096 + (wc * 64 + n * 16 + l15) * 32 + l4s8];
        #pragma unroll
        for (int m = 0; m < 4; ++m)
            #pragma unroll
            for (int n = 0; n < 4; ++n)
                acc[m][n] = __builtin_amdgcn_mfma_f32_16x16x32_bf16(af[m], bfv[n], acc[m][n], 0, 0, 0);
    }

    #pragma unroll
    for (int m = 0; m < 4; ++m)
        #pragma unroll
        for (int j = 0; j < 4; ++j) {
            long row = wr * 64 + m * 16 + l4 * 4 + j;
            #pragma unroll
            for (int n = 0; n < 4; ++n)
                Cb[row * 128 + wc * 64 + n * 16 + l15] = f2bf(acc[m][n][j]);
        }
}

// ---------------------------------------------------------------------------
// sm_tv: causal row softmax (16384 blocks, one wave/row — max TLP) +
// transpose_veff tail (4096 blocks). Independent.
// ---------------------------------------------------------------------------
__global__ __launch_bounds__(256) void sm_tv(
    ushort_t* __restrict__ Spk,
    const ushort_t* __restrict__ Veff, ushort_t* __restrict__ VeffT)
{
    const int id = blockIdx.x;
    if (id >= 16384) {                        // transpose_veff
        int idx = (id - 16384) * 256 + threadIdx.x;
        int c = idx & 2047, rest = idx >> 11;
        int t8 = rest & 127, b = rest >> 7;
        ushort_t v[8];
        #pragma unroll
        for (int j = 0; j < 8; ++j)
            v[j] = Veff[((long)b * Tn + t8 * 8 + j) * 2048 + c];
        *(uint4*)&VeffT[((long)b * 2048 + c) * Tn + t8 * 8] = *(const uint4*)v;
        return;
    }
    const int wid  = threadIdx.x >> 6;
    const int lane = threadIdx.x & 63;
    const int r = id * 4 + wid;               // 0..65535
    const int z = r >> 10, t = r & 1023;
    const int ti = t >> 7;
    const int nc = ti + 1;
    ushort_t* base = Spk + (long)z * 589824 + (long)(ti * (ti + 1) / 2) * 16384
                        + (t & 127) * 128;
    const float SCL = ATT_SCALE * LOG2E;

    float p0[8], p1[8];
    float mx = -INFINITY;
    #pragma unroll
    for (int c = 0; c < 8; ++c) {
        p0[c] = -INFINITY; p1[c] = -INFINITY;
        if (c < nc) {
            uint_t u = *(const uint_t*)&base[c * 16384 + lane * 2];
            int kv = c * 128 + lane * 2;
            float a  = __uint_as_float(u << 16);
            float bb = __uint_as_float(u & 0xffff0000u);
            if (kv     <= t) p0[c] = a  * SCL;
            if (kv + 1 <= t) p1[c] = bb * SCL;
            mx = fmaxf(mx, fmaxf(p0[c], p1[c]));
        }
    }
    #pragma unroll
    for (int off = 32; off >= 1; off >>= 1) mx = fmaxf(mx, __shfl_xor(mx, off));
    float s = 0.f;
    #pragma unroll
    for (int c = 0; c < 8; ++c) {
        p0[c] = exp2f(p0[c] - mx);
        p1[c] = exp2f(p1[c] - mx);
        if (c < nc) s += p0[c] + p1[c];
    }
    #pragma unroll
    for (int off = 32; off >= 1; off >>= 1) s += __shfl_xor(s, off);
    const float inv = 1.f / s;
    #pragma unroll
    for (int c = 0; c < 8; ++c) if (c < nc) {
        uint_t o = (uint_t)f2bf(p0[c] * inv) | ((uint_t)f2bf(p1[c] * inv) << 16);
        *(uint_t*)&base[c * 16384 + lane * 2] = o;
    }
}

// ---------------------------------------------------------------------------
// attn_pv: out = P @ VeffT_h^T (f32). 512 blocks + XCD swizzle.
// ---------------------------------------------------------------------------
__global__ __launch_bounds__(256, 2) void attn_pv_gemm(
    const ushort_t* __restrict__ Spk, const ushort_t* __restrict__ VeffT,
    float* __restrict__ out)
{
    __shared__ ushort_t As[3 * 4096];
    __shared__ ushort_t Bs[3 * 4096];
    const int id  = blockIdx.x;
    const int sid = (id & 7) * 64 + (id >> 3);
    const int ti = sid & 7, z = sid >> 3;
    const int tid  = threadIdx.x;
    const int lane = tid & 63;
    const int w    = tid >> 6;
    const int l15 = lane & 15, l4 = lane >> 4;
    const int wr = w >> 1, wc = w & 1;
    const int srow = lane >> 2;
    const int scolsw = (((lane & 3) ^ ((srow >> 1) & 3)) * 8);
    const int l4s8 = (l4 ^ ((l15 >> 1) & 3)) * 8;
    const int h = z >> 2, b = z & 3;
    const int nT = (ti + 1) * 4;
    const ushort_t* Abase = Spk + (long)z * 589824 + (long)(ti * (ti + 1) / 2) * 16384;
    const ushort_t* Bb = VeffT + ((long)b * 2048 + h * 128) * 1024;
    float* Cb = out + ((long)b * 1024 + ti * 128) * 2048 + h * 128;

    auto stage = [&](int t) {
        const int buf = t % 3;
        const int k0 = t * 32;
        const ushort_t* At = Abase + (k0 >> 7) * 16384 + (k0 & 127);
        #pragma unroll
        for (int i = 0; i < 2; ++i) {
            int r = w * 32 + i * 16;
            gload_lds16(At + (long)(r + srow) * 128 + scolsw, &As[buf * 4096 + r * 32]);
            gload_lds16(Bb + (long)(r + srow) * 1024 + k0 + scolsw, &Bs[buf * 4096 + r * 32]);
        }
    };

    f32x4 acc[4][4];
    #pragma unroll
    for (int m = 0; m < 4; ++m)
        #pragma unroll
        for (int n = 0; n < 4; ++n) acc[m][n] = (f32x4){0.f, 0.f, 0.f, 0.f};

    stage(0); stage(1);
    for (int t = 0; t < nT; ++t) {
        pipe_wait4(t + 1 >= nT);
        if (t + 2 < nT) stage(t + 2);
        const int buf = t % 3;
        bf16x8 af[4], bfv[4];
        #pragma unroll
        for (int m = 0; m < 4; ++m)
            af[m] = *(const bf16x8*)&As[buf * 4096 + (wr * 64 + m * 16 + l15) * 32 + l4s8];
        #pragma unroll
        for (int n = 0; n < 4; ++n)
            bfv[n] = *(const bf16x8*)&Bs[buf * 4096 + (wc * 64 + n * 16 + l15) * 32 + l4s8];
        #pragma unroll
        for (int m = 0; m < 4; ++m)
            #pragma unroll
            for (int n = 0; n < 4; ++n)
                acc[m][n] = __builtin_amdgcn_mfma_f32_16x16x32_bf16(af[m], bfv[n], acc[m][n], 0, 0, 0);
    }

    #pragma unroll
    for (int m = 0; m < 4; ++m)
        #pragma unroll
        for (int j = 0; j < 4; ++j) {
            long row = wr * 64 + m * 16 + l4 * 4 + j;
            #pragma unroll
            for (int n = 0; n < 4; ++n)
                Cb[row * 2048 + wc * 64 + n * 16 + l15] = acc[m][n][j];
        }
}

// ---------------------------------------------------------------------------
// prep_all: fused conversions + transposes (range dispatch).
// ---------------------------------------------------------------------------
__global__ __launch_bounds__(256) void prep_all(
    const float* __restrict__ x,    const float* __restrict__ Wdq,
    const float* __restrict__ Wdkv, const float* __restrict__ Wkr,
    const float* __restrict__ Wqr,  const float* __restrict__ Wo,
    const float* __restrict__ Wuk,  const float* __restrict__ Wuq,
    const float* __restrict__ Wuv,
    ushort_t* __restrict__ xb, ushort_t* __restrict__ WB1,
    ushort_t* __restrict__ WB2, ushort_t* __restrict__ Wo_b,
    ushort_t* __restrict__ WB3, ushort_t* __restrict__ WuvT_b)
{
    const int bid = blockIdx.x;
    const int t = threadIdx.x;

    if (bid >= 9600) {
        __shared__ float tile[64][65];
        const float* in; ushort_t* outp; int ldin, R, c0, r0;
        if (bid < 10368) { int l = bid - 9600;  in = Wuq; outp = WB2;    ldin = 2048; R = 1536; c0 = (l % 32) * 64; r0 = (l / 32) * 64; }
        else             { int l = bid - 10368; in = Wuv; outp = WuvT_b; ldin = 512;  R = 2048; c0 = (l % 8) * 64;  r0 = (l / 8) * 64; }
        #pragma unroll
        for (int i = 0; i < 4; ++i) {
            int idx = t + i * 256;
            int r = idx >> 4, c4 = idx & 15;
            float4 v = *(const float4*)&in[(long)(r0 + r) * ldin + c0 + c4 * 4];
            tile[r][c4 * 4 + 0] = v.x; tile[r][c4 * 4 + 1] = v.y;
            tile[r][c4 * 4 + 2] = v.z; tile[r][c4 * 4 + 3] = v.w;
        }
        __syncthreads();
        #pragma unroll
        for (int i = 0; i < 4; ++i) {
            int idx = t + i * 256;
            int c = idx >> 4, r4 = idx & 15;
            ushort_t p[4];
            #pragma unroll
            for (int j = 0; j < 4; ++j) p[j] = f2bf(tile[r4 * 4 + j][c]);
            *(uint2*)&outp[(long)(c0 + c) * R + r0 + r4 * 4] = *(const uint2*)p;
        }
        return;
    }

    const float* src = nullptr; ushort_t* dst;
    if      (bid < 4096) { src = x    + (long)bid * 2048;          dst = xb   + (long)bid * 2048; }
    else if (bid < 5632) { long b = bid - 4096; src = Wdq  + b * 2048; dst = WB1 + b * 2048; }
    else if (bid < 6144) { long b = bid - 5632; src = Wdkv + b * 2048; dst = WB1 + 3145728 + b * 2048; }
    else if (bid < 6208) { long b = bid - 6144; src = Wkr  + b * 2048; dst = WB1 + 4194304 + b * 2048; }
    else if (bid < 6272) { long b = bid - 6208;                        dst = WB1 + 4325376 + b * 2048; }
    else if (bid < 7040) { long b = bid - 6272; src = Wqr  + b * 2048; dst = WB2 + 3145728 + b * 2048; }
    else if (bid < 9088) { long b = bid - 7040; src = Wo   + b * 2048; dst = Wo_b + b * 2048; }
    else                 { long b = bid - 9088; src = Wuk  + b * 2048; dst = WB3 + b * 2048; }

    const long i = (long)t * 8;
    if (!src) { *(uint4*)&dst[i] = make_uint4(0, 0, 0, 0); return; }
    float4 a = *(const float4*)&src[i];
    float4 b4 = *(const float4*)&src[i + 4];
    ushort_t p[8] = {f2bf(a.x), f2bf(a.y), f2bf(a.z), f2bf(a.w),
                     f2bf(b4.x), f2bf(b4.y), f2bf(b4.z), f2bf(b4.w)};
    *(uint4*)&dst[i] = *(const uint4*)p;
}

// ---------------------------------------------------------------------------
extern "C" void kernel_launch(void* const* d_in, const int* in_sizes, int n_in,
                              void* d_out, int out_size, void* d_ws, size_t ws_size,
                              hipStream_t stream)
{
    (void)in_sizes; (void)n_in; (void)out_size; (void)ws_size;
    const float* x     = (const float*)d_in[0];
    const float* cosT  = (const float*)d_in[1];
    const float* sinT  = (const float*)d_in[2];
    const float* W_dq  = (const float*)d_in[3];
    const float* W_uq  = (const float*)d_in[4];
    const float* W_dkv = (const float*)d_in[5];
    const float* W_uk  = (const float*)d_in[6];
    const float* W_uv  = (const float*)d_in[7];
    const float* W_qr  = (const float*)d_in[8];
    const float* W_kr  = (const float*)d_in[9];
    const float* W_o   = (const float*)d_in[10];
    float* out = (float*)d_out;

    // ---- workspace: 79,953,920 ushorts = 159.9 MB ----
    ushort_t* ws = (ushort_t*)d_ws;
    ushort_t* xb     = ws;                              // 8388608
    ushort_t* WB1    = ws + 8388608;                    // 4456448  [2176][2048]
    ushort_t* WB2    = ws + 12845056;                   // 4718592  [3072][1536] = WuqT|Wqr
    ushort_t* Wo_b   = ws + 17563648;                   // 4194304  [2048][2048]
    ushort_t* WuvT_b = ws + 21757952;                   // 1048576  [512][2048]
    ushort_t* cq_b   = ws + 22806528;                   // 6291456  [4096][1536]
    ushort_t* WB3    = ws + 29097984;                   // 2097152  [4096][512] = Wuk|Mt
    ushort_t* Spk    = ws;                              // 37748736 [64 z][36][128][128]
    // PERSISTENT:
    ushort_t* qnom   = ws + 39583744;                   // 8388608
    ushort_t* qr_b   = ws + 47972352;                   // 4194304
    ushort_t* kabs   = ws + 52166656;                   // 8388608
    ushort_t* kfull  = ws + 60555264;                   // 2621440  [4096][640]
    ushort_t* VeffT  = ws + 63176704;                   // 8388608  [4][2048][1024]
    ushort_t* Veff   = ws + 71565312;                   // 8388608  (lives past attn_s)
    ushort_t* Mtb    = WB3 + 1048576;

    dim3 blk(256, 1, 1);

    // 1) conversions + transposes (fused)
    prep_all<<<dim3(10624), blk, 0, stream>>>(
        x, W_dq, W_dkv, W_kr, W_qr, W_o, W_uk, W_uq, W_uv,
        xb, WB1, WB2, Wo_b, WB3, WuvT_b);

    // 2) group1 (fused rope_kr) + Mt
    g1_mt<<<dim3(608), blk, 0, stream>>>(xb, WB1, cq_b, kfull, Wo_b, WuvT_b, Mtb,
                                         cosT, sinT);

    // 3) group2 (fused rope_qr) + group3
    g23<<<dim3(1792), blk, 0, stream>>>(cq_b, WB2, qnom, qr_b, kfull, WB3,
                                        kabs, Veff, cosT, sinT);

    // 4) attn_s (pure GEMM)
    attn_s_gemm<<<dim3(2304), blk, 0, stream>>>(qnom, qr_b, kabs, kfull, Spk);

    // 5) softmax (max TLP) + transpose_veff tail
    sm_tv<<<dim3(16384 + 4096), blk, 0, stream>>>(Spk, Veff, VeffT);

    // 6) PV -> out
    attn_pv_gemm<<<dim3(512), blk, 0, stream>>>(Spk, VeffT, out);
}